// Round 1
// baseline (314.346 us; speedup 1.0000x reference)
//
#include <hip/hip_runtime.h>
#include <math.h>

// Problem constants (fixed by setup_inputs): B=4096 sessions, T=2048 trials.
#define B_SESS 4096
#define T_TR   2048
#define NCH    256   // chunks per session (one per thread)
#define CL     8     // trials per chunk
#define NG     32    // scan groups
#define GL     8     // chunks per group

// Recurrence per (session, side):  v' = (1-coef)*v + rhs
//   coef = sum_i alpha_i * w_i,  rhs = sum_i alpha_i * w_i * k_i
//   diff = s1 - s0*v,  delta = rhs - coef*v,  new_v = v + delta
// where w = [same*o, same*no, other*o, other*no], left: same=cl, right: same=cr.

__global__ __launch_bounds__(256) void qvalue_kernel(
    const float* __restrict__ inp,
    const float* __restrict__ p_asr, const float* __restrict__ p_asu,
    const float* __restrict__ p_adr, const float* __restrict__ p_adu,
    const float* __restrict__ p_ksr, const float* __restrict__ p_ksu,
    const float* __restrict__ p_kdr, const float* __restrict__ p_kdu,
    float* __restrict__ out)
{
    // Input staged in LDS, chunk-transposed: idx(t,c) = ((t%CL)*NCH + t/CL)*3 + c
    // -> inner-step reads at word (3*j + c) mod 32 across lanes: conflict-free.
    __shared__ float sIn[T_TR * 3];          // 24 KB
    __shared__ float sA[NCH * 2];            // chunk map A, per side
    __shared__ float sB[NCH * 2];            // chunk map B, per side
    __shared__ float sGA[NG * 2];            // group map A
    __shared__ float sGB[NG * 2];            // group map B
    __shared__ float sGV[NG * 2];            // group start v
    __shared__ float sV[NCH * 2];            // chunk start v

    const int s   = blockIdx.x;
    const int tid = threadIdx.x;

    // ---- coalesced global -> LDS (swizzled scatter) ----
    const float4* in4 = (const float4*)(inp + (size_t)s * (T_TR * 3));
    #pragma unroll
    for (int k = 0; k < 6; ++k) {
        int p4 = k * 256 + tid;
        float4 w = in4[p4];
        float vals[4] = {w.x, w.y, w.z, w.w};
        #pragma unroll
        for (int e = 0; e < 4; ++e) {
            int p = p4 * 4 + e;
            int t = p / 3;            // compiler: magic-mul
            int c = p - t * 3;
            sIn[((t & (CL - 1)) * NCH + (t >> 3)) * 3 + c] = vals[e];
        }
    }

    // ---- parameters (uniform, cheap redundant compute) ----
    float a0 = 1.f / (1.f + expf(-p_asr[0]));
    float a1 = 1.f / (1.f + expf(-p_asu[0]));
    float a2 = 1.f / (1.f + expf(-p_adr[0]));
    float a3 = 1.f / (1.f + expf(-p_adu[0]));
    float k0 = p_ksr[0], k1 = p_ksu[0], k2 = p_kdr[0], k3 = p_kdu[0];
    float b0 = a0 * k0, b1 = a1 * k1, b2 = a2 * k2, b3 = a3 * k3;

    __syncthreads();

    // ---- Phase A: per-chunk affine map (both sides), chunk j = tid ----
    {
        const int j = tid;
        float AL = 1.f, BL = 0.f, AR = 1.f, BR = 0.f;
        #pragma unroll
        for (int l = 0; l < CL; ++l) {
            int base = (l * NCH + j) * 3;
            float cl = sIn[base], cr = sIn[base + 1], o = sIn[base + 2];
            float no = 1.f - o;
            float m0 = cl * o, m1 = cl * no, m2 = cr * o, m3 = cr * no;
            float coefL = a0 * m0 + a1 * m1 + a2 * m2 + a3 * m3;
            float rhsL  = b0 * m0 + b1 * m1 + b2 * m2 + b3 * m3;
            float coefR = a0 * m2 + a1 * m3 + a2 * m0 + a3 * m1;
            float rhsR  = b0 * m2 + b1 * m3 + b2 * m0 + b3 * m1;
            float gL = 1.f - coefL, gR = 1.f - coefR;
            AL = AL * gL;  BL = BL * gL + rhsL;
            AR = AR * gR;  BR = BR * gR + rhsR;
        }
        sA[j * 2 + 0] = AL;  sB[j * 2 + 0] = BL;
        sA[j * 2 + 1] = AR;  sB[j * 2 + 1] = BR;
    }
    __syncthreads();

    // ---- group summaries: 64 threads, (g = tid>>1, sd = tid&1) ----
    if (tid < NG * 2) {
        int g = tid >> 1, sd = tid & 1;
        float A = 1.f, Bc = 0.f;
        #pragma unroll
        for (int q = 0; q < GL; ++q) {
            int j = g * GL + q;
            float a = sA[j * 2 + sd], b = sB[j * 2 + sd];
            A = a * A;  Bc = a * Bc + b;
        }
        sGA[g * 2 + sd] = A;  sGB[g * 2 + sd] = Bc;
    }
    __syncthreads();

    // ---- serial scan over 32 groups (2 lanes) ----
    if (tid < 2) {
        int sd = tid;
        float v = 0.f;
        #pragma unroll
        for (int g = 0; g < NG; ++g) {
            sGV[g * 2 + sd] = v;
            v = sGA[g * 2 + sd] * v + sGB[g * 2 + sd];
        }
    }
    __syncthreads();

    // ---- chunk start values within groups ----
    if (tid < NG * 2) {
        int g = tid >> 1, sd = tid & 1;
        float v = sGV[g * 2 + sd];
        #pragma unroll
        for (int q = 0; q < GL; ++q) {
            int j = g * GL + q;
            sV[j * 2 + sd] = v;
            v = sA[j * 2 + sd] * v + sB[j * 2 + sd];
        }
    }
    __syncthreads();

    // ---- Phase C: replay chunk, write v/diff/delta ----
    {
        const int j = tid;
        float vL = sV[j * 2 + 0], vR = sV[j * 2 + 1];
        float vb[2 * CL], fb[2 * CL], db[2 * CL];
        #pragma unroll
        for (int l = 0; l < CL; ++l) {
            int base = (l * NCH + j) * 3;
            float cl = sIn[base], cr = sIn[base + 1], o = sIn[base + 2];
            float no = 1.f - o;
            float m0 = cl * o, m1 = cl * no, m2 = cr * o, m3 = cr * no;
            float coefL = a0 * m0 + a1 * m1 + a2 * m2 + a3 * m3;
            float rhsL  = b0 * m0 + b1 * m1 + b2 * m2 + b3 * m3;
            float coefR = a0 * m2 + a1 * m3 + a2 * m0 + a3 * m1;
            float rhsR  = b0 * m2 + b1 * m3 + b2 * m0 + b3 * m1;
            float s0  = m0 + m1 + m2 + m3;
            float s1L = k0 * m0 + k1 * m1 + k2 * m2 + k3 * m3;
            float s1R = k0 * m2 + k1 * m3 + k2 * m0 + k3 * m1;
            float dL = rhsL - coefL * vL;
            float dR = rhsR - coefR * vR;
            float fL = s1L - s0 * vL;
            float fR = s1R - s0 * vR;
            vL += dL;  vR += dR;
            vb[2 * l] = vL;  vb[2 * l + 1] = vR;
            fb[2 * l] = fL;  fb[2 * l + 1] = fR;
            db[2 * l] = dL;  db[2 * l + 1] = dR;
        }
        const size_t N2   = (size_t)B_SESS * T_TR * 2;   // elems per output array
        const size_t boff = (size_t)s * (T_TR * 2) + (size_t)j * (CL * 2);
        float4* ov = (float4*)(out + boff);              // out_v
        float4* of = (float4*)(out + N2 + boff);         // out_diff
        float4* od = (float4*)(out + 2 * N2 + boff);     // out_delta
        #pragma unroll
        for (int q = 0; q < (2 * CL) / 4; ++q) {
            ov[q] = make_float4(vb[4 * q], vb[4 * q + 1], vb[4 * q + 2], vb[4 * q + 3]);
            of[q] = make_float4(fb[4 * q], fb[4 * q + 1], fb[4 * q + 2], fb[4 * q + 3]);
            od[q] = make_float4(db[4 * q], db[4 * q + 1], db[4 * q + 2], db[4 * q + 3]);
        }
    }
}

extern "C" void kernel_launch(void* const* d_in, const int* in_sizes, int n_in,
                              void* d_out, int out_size, void* d_ws, size_t ws_size,
                              hipStream_t stream) {
    (void)in_sizes; (void)n_in; (void)out_size; (void)d_ws; (void)ws_size;
    qvalue_kernel<<<B_SESS, 256, 0, stream>>>(
        (const float*)d_in[0],
        (const float*)d_in[1], (const float*)d_in[2],
        (const float*)d_in[3], (const float*)d_in[4],
        (const float*)d_in[5], (const float*)d_in[6],
        (const float*)d_in[7], (const float*)d_in[8],
        (float*)d_out);
}

// Round 2
// 296.828 us; speedup vs baseline: 1.0590x; 1.0590x over previous
//
#include <hip/hip_runtime.h>
#include <math.h>

// Problem constants (fixed by setup_inputs): B=4096 sessions, T=2048 trials.
#define B_SESS 4096
#define T_TR   2048
#define NCH    256   // chunks per session (one per thread)
#define CL     8     // trials per chunk

// Recurrence per (session, side):  v' = (1-coef)*v + rhs   (affine in v)
//   coef = sum_i alpha_i*w_i,  rhs = sum_i alpha_i*w_i*k_i
//   diff = s1 - s0*v,  delta = rhs - coef*v,  new_v = v + delta
// Chunked scan: per-chunk affine map composed via in-wave shuffle scan.

__global__ __launch_bounds__(256, 4) void qvalue_kernel(
    const float* __restrict__ inp,
    const float* __restrict__ p_asr, const float* __restrict__ p_asu,
    const float* __restrict__ p_adr, const float* __restrict__ p_adu,
    const float* __restrict__ p_ksr, const float* __restrict__ p_ksu,
    const float* __restrict__ p_kdr, const float* __restrict__ p_kdu,
    float* __restrict__ out)
{
    // Input staged in LDS, chunk-transposed: idx(t,c) = ((t%CL)*NCH + t/CL)*3 + c
    // -> inner-step reads at bank (3j+c)%32 across lanes (3 coprime 32): 2-way max = free.
    // After replay, sIn is reused as the per-wave store-transpose buffer (4 KB/wave).
    __shared__ float sIn[T_TR * 3];   // 24 KB
    __shared__ float sWT[4 * 4];      // wave-total maps {AL,BL,AR,BR} per wave

    const int s    = blockIdx.x;
    const int tid  = threadIdx.x;
    const int lane = tid & 63;
    const int w    = tid >> 6;        // wave id (0..3), wave-uniform

    // ---- coalesced global -> LDS (swizzled scatter) ----
    const float4* in4 = (const float4*)(inp + (size_t)s * (T_TR * 3));
    #pragma unroll
    for (int k = 0; k < 6; ++k) {
        int p4 = k * 256 + tid;
        float4 wv = in4[p4];
        float vals[4] = {wv.x, wv.y, wv.z, wv.w};
        #pragma unroll
        for (int e = 0; e < 4; ++e) {
            int p = p4 * 4 + e;
            int t = p / 3;            // magic-mul
            int c = p - t * 3;
            sIn[((t & (CL - 1)) * NCH + (t >> 3)) * 3 + c] = vals[e];
        }
    }

    // ---- parameters (uniform, cheap redundant compute) ----
    float a0 = 1.f / (1.f + expf(-p_asr[0]));
    float a1 = 1.f / (1.f + expf(-p_asu[0]));
    float a2 = 1.f / (1.f + expf(-p_adr[0]));
    float a3 = 1.f / (1.f + expf(-p_adu[0]));
    float k0 = p_ksr[0], k1 = p_ksu[0], k2 = p_kdr[0], k3 = p_kdu[0];
    float b0 = a0 * k0, b1 = a1 * k1, b2 = a2 * k2, b3 = a3 * k3;

    __syncthreads();

    // ---- Phase A: per-chunk affine map (both sides), chunk j = tid ----
    float AL = 1.f, BL = 0.f, AR = 1.f, BR = 0.f;
    #pragma unroll
    for (int l = 0; l < CL; ++l) {
        int base = (l * NCH + tid) * 3;
        float cl = sIn[base], cr = sIn[base + 1], o = sIn[base + 2];
        float no = 1.f - o;
        float m0 = cl * o, m1 = cl * no, m2 = cr * o, m3 = cr * no;
        float coefL = a0 * m0 + a1 * m1 + a2 * m2 + a3 * m3;
        float rhsL  = b0 * m0 + b1 * m1 + b2 * m2 + b3 * m3;
        float coefR = a0 * m2 + a1 * m3 + a2 * m0 + a3 * m1;
        float rhsR  = b0 * m2 + b1 * m3 + b2 * m0 + b3 * m1;
        float gL = 1.f - coefL, gR = 1.f - coefR;
        AL = AL * gL;  BL = BL * gL + rhsL;
        AR = AR * gR;  BR = BR * gR + rhsR;
    }

    // ---- in-wave inclusive scan of affine maps (Hillis-Steele, 6 steps) ----
    // compose: x_j = x_j o x_{j-d}  (earlier map applied first)
    #pragma unroll
    for (int d = 1; d < 64; d <<= 1) {
        float tAL = __shfl_up(AL, d, 64);
        float tBL = __shfl_up(BL, d, 64);
        float tAR = __shfl_up(AR, d, 64);
        float tBR = __shfl_up(BR, d, 64);
        if (lane >= d) {
            BL = AL * tBL + BL;  AL = AL * tAL;
            BR = AR * tBR + BR;  AR = AR * tAR;
        }
    }
    if (lane == 63) {
        sWT[w * 4 + 0] = AL;  sWT[w * 4 + 1] = BL;
        sWT[w * 4 + 2] = AR;  sWT[w * 4 + 3] = BR;
    }
    // in-wave exclusive map (shift by one lane; identity at lane 0)
    float eAL = __shfl_up(AL, 1, 64), eBL = __shfl_up(BL, 1, 64);
    float eAR = __shfl_up(AR, 1, 64), eBR = __shfl_up(BR, 1, 64);
    if (lane == 0) { eAL = 1.f; eBL = 0.f; eAR = 1.f; eBR = 0.f; }

    __syncthreads();

    // ---- combine wave-exclusive prefix (v0 = 0) ----
    float vbL = 0.f, vbR = 0.f;
    for (int ww = 0; ww < w; ++ww) {          // wave-uniform loop, <=3 iters
        vbL = sWT[ww * 4 + 0] * vbL + sWT[ww * 4 + 1];
        vbR = sWT[ww * 4 + 2] * vbR + sWT[ww * 4 + 3];
    }
    float vL = eAL * vbL + eBL;
    float vR = eAR * vbR + eBR;

    // ---- Phase C: replay chunk into register buffers ----
    float vb[2 * CL], fb[2 * CL], db[2 * CL];
    #pragma unroll
    for (int l = 0; l < CL; ++l) {
        int base = (l * NCH + tid) * 3;
        float cl = sIn[base], cr = sIn[base + 1], o = sIn[base + 2];
        float no = 1.f - o;
        float m0 = cl * o, m1 = cl * no, m2 = cr * o, m3 = cr * no;
        float coefL = a0 * m0 + a1 * m1 + a2 * m2 + a3 * m3;
        float rhsL  = b0 * m0 + b1 * m1 + b2 * m2 + b3 * m3;
        float coefR = a0 * m2 + a1 * m3 + a2 * m0 + a3 * m1;
        float rhsR  = b0 * m2 + b1 * m3 + b2 * m0 + b3 * m1;
        float s0  = m0 + m1 + m2 + m3;
        float s1L = k0 * m0 + k1 * m1 + k2 * m2 + k3 * m3;
        float s1R = k0 * m2 + k1 * m3 + k2 * m0 + k3 * m1;
        float dL = rhsL - coefL * vL;
        float dR = rhsR - coefR * vR;
        float fL = s1L - s0 * vL;
        float fR = s1R - s0 * vR;
        vL += dL;  vR += dR;
        vb[2 * l] = vL;  vb[2 * l + 1] = vR;
        fb[2 * l] = fL;  fb[2 * l + 1] = fR;
        db[2 * l] = dL;  db[2 * l + 1] = dR;
    }

    // ---- coalesced stores via per-wave LDS transpose (reuse sIn) ----
    __syncthreads();                     // everyone done reading sIn
    float* rb = sIn + (w << 10);         // 1024 floats (4 KB) per wave
    const size_t N2    = (size_t)B_SESS * T_TR * 2;
    const size_t gbase = (size_t)s * (T_TR * 2) + ((size_t)w << 10);

    float4* ov = (float4*)(out + gbase);
    float4* of = (float4*)(out + N2 + gbase);
    float4* od = (float4*)(out + 2 * N2 + gbase);

    // round 1: v
    #pragma unroll
    for (int q = 0; q < 4; ++q)
        ((float4*)(rb + lane * 16))[q] =
            make_float4(vb[4 * q], vb[4 * q + 1], vb[4 * q + 2], vb[4 * q + 3]);
    __syncthreads();
    #pragma unroll
    for (int q = 0; q < 4; ++q)
        ov[q * 64 + lane] = ((const float4*)rb)[q * 64 + lane];
    __syncthreads();

    // round 2: diff
    #pragma unroll
    for (int q = 0; q < 4; ++q)
        ((float4*)(rb + lane * 16))[q] =
            make_float4(fb[4 * q], fb[4 * q + 1], fb[4 * q + 2], fb[4 * q + 3]);
    __syncthreads();
    #pragma unroll
    for (int q = 0; q < 4; ++q)
        of[q * 64 + lane] = ((const float4*)rb)[q * 64 + lane];
    __syncthreads();

    // round 3: delta
    #pragma unroll
    for (int q = 0; q < 4; ++q)
        ((float4*)(rb + lane * 16))[q] =
            make_float4(db[4 * q], db[4 * q + 1], db[4 * q + 2], db[4 * q + 3]);
    __syncthreads();
    #pragma unroll
    for (int q = 0; q < 4; ++q)
        od[q * 64 + lane] = ((const float4*)rb)[q * 64 + lane];
}

extern "C" void kernel_launch(void* const* d_in, const int* in_sizes, int n_in,
                              void* d_out, int out_size, void* d_ws, size_t ws_size,
                              hipStream_t stream) {
    (void)in_sizes; (void)n_in; (void)out_size; (void)d_ws; (void)ws_size;
    qvalue_kernel<<<B_SESS, 256, 0, stream>>>(
        (const float*)d_in[0],
        (const float*)d_in[1], (const float*)d_in[2],
        (const float*)d_in[3], (const float*)d_in[4],
        (const float*)d_in[5], (const float*)d_in[6],
        (const float*)d_in[7], (const float*)d_in[8],
        (float*)d_out);
}